// Round 9
// baseline (329.778 us; speedup 1.0000x reference)
//
#include <hip/hip_runtime.h>

#define HH 384
#define WW 384
#define OUTD 370

// ---- R23: +/- shift-pair symmetry -- compute each paired conv ONCE ----
// Ledger: every reshuffle of R13's stream (occupancy R16, barriers R17,
// layout R18, pipeline R19, DS/2 R20, VALU/2 R21/R22) = neutral or worse.
// Only untried lever: REMOVE WORK. Identity (circular roll, exact):
// D_{-v}(p) = D_v(p+v). 99 shifts = 40 +/- pairs (|sx|,|sy|<=4) + 19
// singles (x=-5 or y=-5). Pair: one conv on expanded window (<=28x36),
// D materialized to LDS (DB), consumed at p (shift +v) and p+v (shift -v).
// Conv outputs 0.66x, VALU ~0.7x, 59 slots vs 99.
// Exactness: per-D arithmetic = R13's tap7 chains bitwise; fmin order-free;
// cardinal V-sum buffered and combined in R13's exact order ((c45+c54)+c55)+c64.
// Only phase-2 loss-sum ORDER changes -> absmax ~1e-7 expected (fp32 reorder).
// Safety: all out-of-window reads land inside the LDS block (audited) and
// only into cells never consumed; negative row clamped.
// Banks: all reads/writes consecutive-lane per instruction (conflict-free)
// or <=2-way (free per m136). T2STR=45, DBSTR=41 odd.
#define TW 32
#define TH 24
#define LSTR 47
#define LROWS 39
#define LSZ (LROWS * LSTR)     // 1833
#define T2STR 45               // 44 cols + 1 pad
#define T2SZ (38 * T2STR)      // 1710 per image
#define DBSTR 41               // 40 cols + 1 pad
#define DBSZ (32 * DBSTR)      // 1312 per image
#define NXT 12
#define NYT 16
#define NSH 59

#define G0 0.32465246735834974f   // exp(-9/8)
#define G1 0.6065306597126334f    // exp(-4/8)
#define G2 0.8824969025845955f    // exp(-1/8)
#define KS 0.039788735772973836f  // 1/(8*pi)
#define LOG2E 1.4426950408889634f

__device__ __forceinline__ float tap7(const float* v)
{
    return fmaf(G0, v[0] + v[6],
           fmaf(G1, v[1] + v[5],
           fmaf(G2, v[2] + v[4], v[3])));
}

// i in [0,36): pair reps y=1..4, x=-4..4 ; [36,40): y=0, x=1..4 ;
// [40,50): singles x=-5, y=-5..4 ; [50,59): singles y=-5, x=-4..4.
__device__ __forceinline__ void shift59(int i, int& sx, int& sy, int& pair)
{
    if (i < 36)      { sy = 1 + i / 9; sx = i % 9 - 4; pair = 1; }
    else if (i < 40) { sy = 0; sx = i - 35; pair = 1; }
    else {
        int j = i - 40;
        if (j < 10) { sx = -5; sy = j - 5; }
        else        { sx = j - 14; sy = -5; }
        pair = 0;
    }
}

__device__ __forceinline__ void load_tile(const float* __restrict__ img,
                                          int oy0, int ox0, float* L, int tid)
{
    for (int i = tid; i < LSZ; i += 256) {
        int r = i / LSTR, c = i - r * LSTR;
        int gr = oy0 + r; if (gr >= HH) gr -= HH;   // circular wrap
        int gc = ox0 + c; if (gc >= WW) gc -= WW;
        L[i] = img[gr * WW + gc];
    }
}

extern "C" __global__ void __launch_bounds__(256, 3)
mind_fused(const float* __restrict__ pred, const float* __restrict__ gt,
           float* __restrict__ out)
{
    __shared__ float LP[LSZ];
    __shared__ float LG[LSZ];
    __shared__ float T2[2][T2SZ];   // horiz-tapped diffsq, abs coords [38][44]
    __shared__ float DB[2][DBSZ];   // D window, abs coords [32][40]
    __shared__ float wred[4];
    const int tid = threadIdx.x;
    const int b = blockIdx.y;
    const int oy0 = ((int)blockIdx.x / NXT) * TH;
    const int ox0 = ((int)blockIdx.x % NXT) * TW;

    load_tile(pred + (size_t)b * HH * WW, oy0, ox0, LP, tid);
    load_tile(gt   + (size_t)b * HH * WW, oy0, ox0, LG, tid);

    // horiz: 228 units = 2 img x 38 abs-rows x 3 col-segs (12 outputs each)
    const bool hasH = tid < 228;
    const int himg = hasH ? (tid / 114) : 0;
    const int hu = tid - himg * 114;
    const int har = hu / 3;            // 0..37
    const int hseg = hu - har * 3;     // 0..2
    const float* Lh = himg ? LG : LP;

    // consume: R13 pixel map (32 cols x 8 strips of 3 rows, both images)
    const int vx = tid & 31, vy0 = (tid >> 5) * 3;

    __syncthreads();

    // ---- stage bodies ----
    auto HORIZ = [&](int sx, int sy, int wx0) {
        if (hasH) {
            const int ccol = wx0 + 12 * hseg + 4;
            int arS = har - sy; arS = arS < 0 ? 0 : arS;   // garbage-safe
            const float* Cp = &Lh[har * LSTR + ccol];
            const float* Sp = &Lh[arS * LSTR + (ccol - sx)];
            float v[18];
#pragma unroll
            for (int t = 0; t < 18; ++t) { float d = Cp[t] - Sp[t]; v[t] = d * d; }
            float* o = &T2[himg][har * T2STR + ccol];
#pragma unroll
            for (int k = 0; k < 12; ++k) o[k] = tap7(v + k);
        }
    };

    auto VERT1 = [&](int u, int wx0, int wy0) {
        const int vimg = u / 252;
        const int r2 = u - vimg * 252;
        const int strip = r2 / 36;          // 0..6 (4 D-rows each)
        const int cxr = r2 - strip * 36;    // 0..35
        const int c = wx0 + cxr + 4;        // abs col in [0,40)
        const float* t = &T2[vimg][(wy0 + 4 + strip * 4) * T2STR + c];
        float w[10];
#pragma unroll
        for (int j = 0; j < 10; ++j) w[j] = t[j * T2STR];
        float* o = &DB[vimg][(wy0 + strip * 4 + 4) * DBSTR + c];
#pragma unroll
        for (int jj = 0; jj < 4; ++jj) o[jj * DBSTR] = KS * tap7(w + jj);
    };
    auto VERT = [&](int wx0, int wy0) {
        VERT1(tid, wx0, wy0);
        if (tid < 248) VERT1(tid + 256, wx0, wy0);
    };

    // ---- phase A: dm (min over 99) and exact-order cardinal V-sum ----
    float dm[2][3], vs[2][3], c54[2][3], c55[2][3];
#pragma unroll
    for (int g = 0; g < 2; ++g)
#pragma unroll
        for (int k = 0; k < 3; ++k) { dm[g][k] = 1e30f; vs[g][k] = 0.f; }

    {
        int sx, sy, pair;
        shift59(0, sx, sy, pair);
        int wx0 = pair && sx < 0 ? sx : 0;
        int wy0 = pair && sy < 0 ? sy : 0;
        HORIZ(sx, sy, wx0);
        __syncthreads();
        for (int i = 0; i < NSH; ++i) {
            VERT(wx0, wy0);
            __syncthreads();
            const int csx = sx, csy = sy, cp = pair;
            if (i + 1 < NSH) {
                shift59(i + 1, sx, sy, pair);
                wx0 = pair && sx < 0 ? sx : 0;
                wy0 = pair && sy < 0 ? sy : 0;
                HORIZ(sx, sy, wx0);
            }
            // consume shift i (reads DB at absolute +4-offset coords)
#pragma unroll
            for (int g = 0; g < 2; ++g)
#pragma unroll
            for (int k = 0; k < 3; ++k) {
                const float Dp = DB[g][(vy0 + k + 4) * DBSTR + vx + 4];
                dm[g][k] = fminf(dm[g][k], Dp);
                if (cp) {
                    const float Dm = DB[g][(vy0 + k + csy + 4) * DBSTR + (vx + csx + 4)];
                    dm[g][k] = fminf(dm[g][k], Dm);
                    if (i == 4)  { c54[g][k] = Dm; c55[g][k] = Dp; }      // rep (0,1)
                    if (i == 36) vs[g][k] = ((Dm + c54[g][k]) + c55[g][k]) + Dp; // rep (1,0)
                }
            }
            __syncthreads();
        }
    }

    // loss constants; invalid pixels rv=0 -> e=exp2(0)=1 both -> |ep-eg|=0
    float rv[2][3];
#pragma unroll
    for (int g = 0; g < 2; ++g)
#pragma unroll
    for (int k = 0; k < 3; ++k) {
        const int oy = oy0 + vy0 + k, ox = ox0 + vx;
        const bool valid = (oy < OUTD) && (ox < OUTD);
        rv[g][k] = valid ? LOG2E / (vs[g][k] * 0.25f + 1e-5f) : 0.f;
    }

    // ---- phase B: recompute D, accumulate |exp2((m-D)*rv)p - (...)g| ----
    float acc = 0.f;
    {
        int sx, sy, pair;
        shift59(0, sx, sy, pair);
        int wx0 = pair && sx < 0 ? sx : 0;
        int wy0 = pair && sy < 0 ? sy : 0;
        HORIZ(sx, sy, wx0);
        __syncthreads();
        for (int i = 0; i < NSH; ++i) {
            VERT(wx0, wy0);
            __syncthreads();
            const int csx = sx, csy = sy, cp = pair;
            if (i + 1 < NSH) {
                shift59(i + 1, sx, sy, pair);
                wx0 = pair && sx < 0 ? sx : 0;
                wy0 = pair && sy < 0 ? sy : 0;
                HORIZ(sx, sy, wx0);
            }
#pragma unroll
            for (int k = 0; k < 3; ++k) {
                const float DpP = DB[0][(vy0 + k + 4) * DBSTR + vx + 4];
                const float DpG = DB[1][(vy0 + k + 4) * DBSTR + vx + 4];
                acc += fabsf(exp2f((dm[0][k] - DpP) * rv[0][k])
                           - exp2f((dm[1][k] - DpG) * rv[1][k]));
                if (cp) {
                    const float DmP = DB[0][(vy0 + k + csy + 4) * DBSTR + (vx + csx + 4)];
                    const float DmG = DB[1][(vy0 + k + csy + 4) * DBSTR + (vx + csx + 4)];
                    acc += fabsf(exp2f((dm[0][k] - DmP) * rv[0][k])
                               - exp2f((dm[1][k] - DmG) * rv[1][k]));
                }
            }
            __syncthreads();
        }
    }

#pragma unroll
    for (int off = 32; off > 0; off >>= 1) acc += __shfl_down(acc, off, 64);
    const int lane = tid & 63, wv = tid >> 6;
    if (lane == 0) wred[wv] = acc;
    __syncthreads();
    if (tid == 0) {
        const float SC = (float)(1.0 / 54212400.0);  // 1/(4*370*370*99)
        atomicAdd(out, (wred[0] + wred[1] + wred[2] + wred[3]) * SC);
    }
}

extern "C" void kernel_launch(void* const* d_in, const int* in_sizes, int n_in,
                              void* d_out, int out_size, void* d_ws, size_t ws_size,
                              hipStream_t stream)
{
    (void)in_sizes; (void)n_in; (void)out_size; (void)d_ws; (void)ws_size;
    const float* pred = (const float*)d_in[0];
    const float* gt   = (const float*)d_in[1];
    float* out = (float*)d_out;

    hipMemsetAsync(d_out, 0, sizeof(float), stream);

    dim3 g(NXT * NYT, 4, 1);   // 192 tiles x 4 batch = 768 blocks = 3/CU exact
    mind_fused<<<g, 256, 0, stream>>>(pred, gt, out);
}

// Round 10
// 238.678 us; speedup vs baseline: 1.3817x; 1.3817x over previous
//
#include <hip/hip_runtime.h>

#define HH 384
#define WW 384
#define OUTD 370
#define NSHIFT 99

// ---- R24: vert-first + f32x2 packing + producer/consumer wave split ----
// Two-resource model (fits R13..R23): R13 saturates BOTH VALU (~94%) and LDS
// (~1800cy/2267 window). Cutting one pipe alone never helps (R20 DS-only -> 0;
// R21/R22 VALU-only -> DS binds at same time). R24 cuts both:
//  - s1 (waves 0-1, 114 units = 3 bands x 38 cols): vertical 7-tap FIRST,
//    packed P/G f32x2 (pk codegen proven R21/R22), center column cached in
//    regs (shift-independent); per slot reads 14 shifted values (b64, lanes
//    consecutive-c, conflict-free), writes 8 packed rows (lanes consecutive-c).
//  - s2 (waves 2-3, 96 units = 24 rows x 4 octets): reads 14 CONSECUTIVE
//    f32x2 (7x b128: TSTR2=42 -> 16B-aligned, bank starts 20*dv_r+16*oc
//    spread over 16 residues x2 = free), horizontal 7-tap packed, consumes.
//  - one barrier/slot: s1 builds slot s+1 in buf[p^1] while s2 eats buf[p].
// Indexing = R20 verbatim (absmax 0.0 proven); pk ops are elementwise fp32
// (bitwise = scalar); ascending-s order -> cardinal V-sum exact.
// DS/slot-block ~350-480cy (vs R13 600), VALU ~0.35x.
#define TW 32
#define TH 24
#define LSTR2 47               // L stride in f32x2 (94 dwords == 30 mod 32)
#define LROWS 39
#define LSZ (LROWS * LSTR2)    // 1833 f32x2 = 14.7KB
#define TSTR2 42               // tmp stride in f32x2: 84 dwords == 20 mod 32;
                               // 16B-aligned rows AND 16-residue bank spread
#define TSZ (24 * TSTR2)       // 1008 f32x2 per parity
#define NXT 12
#define NYT 16

#define G0 0.32465246735834974f   // exp(-9/8)
#define G1 0.6065306597126334f    // exp(-4/8)
#define G2 0.8824969025845955f    // exp(-1/8)
#define KS 0.039788735772973836f  // 1/(8*pi)
#define LOG2E 1.4426950408889634f

typedef __attribute__((ext_vector_type(2))) float f32x2;

__device__ __forceinline__ f32x2 tap7p(const f32x2* v)
{
    const f32x2 g0 = (f32x2)(G0), g1 = (f32x2)(G1), g2 = (f32x2)(G2);
    return __builtin_elementwise_fma(g0, v[0] + v[6],
           __builtin_elementwise_fma(g1, v[1] + v[5],
           __builtin_elementwise_fma(g2, v[2] + v[4], v[3])));
}

__device__ __forceinline__ void shift_of(int s, int& sx, int& sy)
{
    int t = (s < 55) ? s : s + 1;    // skip (0,0)
    sx = t / 10 - 5;
    sy = t - (t / 10) * 10 - 5;
}

__device__ __forceinline__ void load_tile2(const float* __restrict__ pr,
                                           const float* __restrict__ gt,
                                           int oy0, int ox0, f32x2* L, int tid)
{
    for (int i = tid; i < LSZ; i += 256) {
        int r = i / LSTR2, c = i - r * LSTR2;
        int gr = oy0 + r; if (gr >= HH) gr -= HH;   // circular wrap
        int gc = ox0 + c; if (gc >= WW) gc -= WW;
        f32x2 t;
        t.x = pr[gr * WW + gc];
        t.y = gt[gr * WW + gc];
        L[i] = t;
    }
}

extern "C" __global__ void __launch_bounds__(256, 3)
mind_fused(const float* __restrict__ pred, const float* __restrict__ gt,
           float* __restrict__ out)
{
    __shared__ f32x2 L2[LSZ];
    __shared__ f32x2 TB[2][TSZ];
    __shared__ float wred[4];
    const int tid = threadIdx.x;
    const int b = blockIdx.y;
    const int oy0 = ((int)blockIdx.x / NXT) * TH;
    const int ox0 = ((int)blockIdx.x % NXT) * TW;

    load_tile2(pred + (size_t)b * HH * WW, gt + (size_t)b * HH * WW,
               oy0, ox0, L2, tid);

    // s1: vertical tap, 114 packed units on waves 0-1
    const bool is1 = tid < 114;
    const int band = is1 ? tid / 38 : 0;
    const int r0 = band * 8;                 // tmp rows r0..r0+7
    const int c1 = is1 ? (tid - band * 38) : 0;   // tmp col 0..37

    // s2: horizontal tap + consume, 96 packed units on waves 2-3
    const bool is2 = (tid >= 128) && (tid < 224);
    const int u2 = is2 ? (tid - 128) : 0;
    const int dv_r = u2 >> 2, oc = u2 & 3;

    __syncthreads();

    // shift-independent center column (rows r0+4..r0+17 at col c1+4), packed
    f32x2 cC[14];
    if (is1) {
#pragma unroll
        for (int t = 0; t < 14; ++t)
            cC[t] = L2[(r0 + 4 + t) * LSTR2 + c1 + 4];
    }

    // s1 body: vertical 7-tap of diffsq for shift s into TB[pw]
    auto S1 = [&](int s, int pw) {
        int sx, sy; shift_of(s, sx, sy);
        const int off = 4 - sy;              // row offset of shifted operand
        const f32x2* Sb = &L2[(r0 + off) * LSTR2 + (c1 + 4 - sx)];
        f32x2 d[14];
#pragma unroll
        for (int a = 0; a < 14; ++a) {
            f32x2 dd = cC[a] - Sb[a * LSTR2];
            d[a] = dd * dd;
        }
        f32x2* w = &TB[pw][r0 * TSTR2 + c1];
#pragma unroll
        for (int k = 0; k < 8; ++k) w[k * TSTR2] = tap7p(d + k);
    };

    // s2 body: horizontal 7-tap -> 8 packed D values
    auto S2 = [&](int pr, f32x2* D) {
        const f32x2* h = &TB[pr][dv_r * TSTR2 + oc * 8];
        f32x2 hv[14];
#pragma unroll
        for (int t = 0; t < 14; ++t) hv[t] = h[t];
        const f32x2 ks = (f32x2)(KS);
#pragma unroll
        for (int k = 0; k < 8; ++k) D[k] = ks * tap7p(hv + k);
    };

    // ---- phase A: dm (min over 99) + cardinal V-sum (ascending s) ----
    f32x2 dm[8], vs[8];
#pragma unroll
    for (int k = 0; k < 8; ++k) { dm[k] = (f32x2)(1e30f); vs[k] = (f32x2)(0.f); }

    if (is1) S1(0, 0);
    __syncthreads();
    int p = 0;
    for (int s = 0; s < NSHIFT; ++s) {
        if (is1 && s + 1 < NSHIFT) S1(s + 1, p ^ 1);   // produce next slot
        if (is2) {
            f32x2 D[8]; S2(p, D);                      // consume current slot
            int sx, sy; shift_of(s, sx, sy);
            const bool card = (sx * sx + sy * sy) == 1;
#pragma unroll
            for (int k = 0; k < 8; ++k) {
                dm[k] = __builtin_elementwise_min(dm[k], D[k]);
                if (card) vs[k] += D[k];
            }
        }
        __syncthreads();   // orders: next-slot writes done; current reads drained
        p ^= 1;
    }

    // loss constants; invalid pixels rv=0 -> ep=eg=exp2(0)=1 -> |ep-eg|=0
    float rvp[8], rvg[8];
#pragma unroll
    for (int k = 0; k < 8; ++k) {
        const int oy = oy0 + dv_r, ox = ox0 + oc * 8 + k;
        const bool valid = is2 && (oy < OUTD) && (ox < OUTD);
        rvp[k] = valid ? LOG2E / (vs[k].x * 0.25f + 1e-5f) : 0.f;
        rvg[k] = valid ? LOG2E / (vs[k].y * 0.25f + 1e-5f) : 0.f;
    }

    // ---- phase B: recompute D, accumulate |exp2((m-D)*rv)p - (...)g| ----
    float acc = 0.f;
    if (is1) S1(0, 0);     // safe: A-loop's final barrier drained slot-98 reads
    __syncthreads();
    p = 0;
    for (int s = 0; s < NSHIFT; ++s) {
        if (is1 && s + 1 < NSHIFT) S1(s + 1, p ^ 1);
        if (is2) {
            f32x2 D[8]; S2(p, D);
#pragma unroll
            for (int k = 0; k < 8; ++k) {
                float ep = exp2f((dm[k].x - D[k].x) * rvp[k]);
                float eg = exp2f((dm[k].y - D[k].y) * rvg[k]);
                acc += fabsf(ep - eg);
            }
        }
        __syncthreads();
        p ^= 1;
    }

#pragma unroll
    for (int off = 32; off > 0; off >>= 1) acc += __shfl_down(acc, off, 64);
    const int lane = tid & 63, wv = tid >> 6;
    if (lane == 0) wred[wv] = acc;
    __syncthreads();
    if (tid == 0) {
        const float SC = (float)(1.0 / 54212400.0);  // 1/(4*370*370*99)
        atomicAdd(out, (wred[0] + wred[1] + wred[2] + wred[3]) * SC);
    }
}

extern "C" void kernel_launch(void* const* d_in, const int* in_sizes, int n_in,
                              void* d_out, int out_size, void* d_ws, size_t ws_size,
                              hipStream_t stream)
{
    (void)in_sizes; (void)n_in; (void)out_size; (void)d_ws; (void)ws_size;
    const float* pred = (const float*)d_in[0];
    const float* gt   = (const float*)d_in[1];
    float* out = (float*)d_out;

    hipMemsetAsync(d_out, 0, sizeof(float), stream);

    dim3 g(NXT * NYT, 4, 1);   // 192 tiles x 4 batch = 768 blocks = 3/CU exact
    mind_fused<<<g, 256, 0, stream>>>(pred, gt, out);
}

// Round 11
// 227.001 us; speedup vs baseline: 1.4528x; 1.0514x over previous
//
#include <hip/hip_runtime.h>

#define HH 384
#define WW 384
#define OUTD 370

// ---- R25: byte-minimal dataflow (R20) + f32x2 pk math (R24) ----
// LDS-BYTE-bandwidth model (128 B/cy/CU) fits R13..R24 exactly:
// R13 29KB/block-period = 90% duty (+ VALU 94%) -> both saturated at 187us;
// R20 18.3KB -> VALU binds (93%); R21/R22/R23 >39KB -> DS overload;
// R24 30.8KB = 96% -> DS-BW-bound at 208us (packing halves instrs, NOT bytes;
// and it dropped the column cache -> s1 re-read 12.8KB/slot).
// R25 = R24 + R20's sC[23] register column-cache (one load per 10-slot
// sx-group): s1 slot reads 12.8KB -> 2.1KB. Total ~20.2KB/block-period
// -> DS ~63%, VALU ~62% (pk) -- first kernel with BOTH pipes < 70%.
// Operand indices bitwise = R24 (absmax 0.0): d[a] = cC[a]-sC[a+off],
// off=9-j. Ascending (gx,j) == ascending s -> cardinal V-sum exact order.
// Hazards: parity double-buffer, 1 barrier/slot: W(s,p) < B_s < R(s,p);
// W(s+2,p) after B_{s+1} > R(s,p). Uniform skip of (0,0) incl. barrier.
// Banks: s1 reads/writes consecutive-c1 b64 (conflict-free); s2 b128 at
// TSTR2=42 (336B rows, 16B-aligned; start residues spread) = 8/bank = min.
#define TW 32
#define TH 24
#define LSTR2 47               // L stride in f32x2
#define LROWS 39
#define LSZ (LROWS * LSTR2)    // 1833 f32x2 = 14.7KB
#define TSTR2 42               // tmp stride in f32x2 (336B: 16B-aligned rows)
#define TSZ (24 * TSTR2)       // 1008 f32x2 = 8.1KB per parity
#define NXT 12
#define NYT 16

#define G0 0.32465246735834974f   // exp(-9/8)
#define G1 0.6065306597126334f    // exp(-4/8)
#define G2 0.8824969025845955f    // exp(-1/8)
#define KS 0.039788735772973836f  // 1/(8*pi)
#define LOG2E 1.4426950408889634f

typedef __attribute__((ext_vector_type(2))) float f32x2;

__device__ __forceinline__ f32x2 tap7p(const f32x2* v)
{
    const f32x2 g0 = (f32x2)(G0), g1 = (f32x2)(G1), g2 = (f32x2)(G2);
    return __builtin_elementwise_fma(g0, v[0] + v[6],
           __builtin_elementwise_fma(g1, v[1] + v[5],
           __builtin_elementwise_fma(g2, v[2] + v[4], v[3])));
}

__device__ __forceinline__ void load_tile2(const float* __restrict__ pr,
                                           const float* __restrict__ gt,
                                           int oy0, int ox0, f32x2* L, int tid)
{
    for (int i = tid; i < LSZ; i += 256) {
        int r = i / LSTR2, c = i - r * LSTR2;
        int gr = oy0 + r; if (gr >= HH) gr -= HH;   // circular wrap
        int gc = ox0 + c; if (gc >= WW) gc -= WW;
        f32x2 t;
        t.x = pr[gr * WW + gc];
        t.y = gt[gr * WW + gc];
        L[i] = t;
    }
}

extern "C" __global__ void __launch_bounds__(256, 3)
mind_fused(const float* __restrict__ pred, const float* __restrict__ gt,
           float* __restrict__ out)
{
    __shared__ __align__(16) f32x2 L2[LSZ];
    __shared__ __align__(16) f32x2 TB[2][TSZ];
    __shared__ float wred[4];
    const int tid = threadIdx.x;
    const int b = blockIdx.y;
    const int oy0 = ((int)blockIdx.x / NXT) * TH;
    const int ox0 = ((int)blockIdx.x % NXT) * TW;

    load_tile2(pred + (size_t)b * HH * WW, gt + (size_t)b * HH * WW,
               oy0, ox0, L2, tid);

    // s1 (producer): vertical tap, 114 packed units on waves 0-1
    const bool is1 = tid < 114;
    const int band = is1 ? tid / 38 : 0;
    const int r0 = band * 8;                       // tmp rows r0..r0+7
    const int c1 = is1 ? (tid - band * 38) : 0;    // tmp col 0..37

    // s2 (consumer): horizontal tap + min/V/loss, 96 units on waves 2-3
    const bool is2 = (tid >= 128) && (tid < 224);
    const int u2 = is2 ? (tid - 128) : 0;
    const int dv_r = u2 >> 2, oc = u2 & 3;

    __syncthreads();

    // shift-independent center column (R24 verbatim)
    f32x2 cC[14];
    if (is1) {
#pragma unroll
        for (int t = 0; t < 14; ++t)
            cC[t] = L2[(r0 + 4 + t) * LSTR2 + c1 + 4];
    }

    // s2 body: horizontal 7-tap -> 8 packed D values (b128 reads)
    auto S2 = [&](int pr, f32x2* D) {
        const float4* h4 = (const float4*)&TB[pr][dv_r * TSTR2 + oc * 8];
        f32x2 hv[14];
#pragma unroll
        for (int t = 0; t < 7; ++t) {
            float4 q = h4[t];
            hv[2 * t].x = q.x; hv[2 * t].y = q.y;
            hv[2 * t + 1].x = q.z; hv[2 * t + 1].y = q.w;
        }
        const f32x2 ks = (f32x2)(KS);
#pragma unroll
        for (int k = 0; k < 8; ++k) D[k] = ks * tap7p(hv + k);
    };

    // ---- phase A: dm (min over 99) + cardinal V-sum (ascending s) ----
    f32x2 dm[8], vs[8];
#pragma unroll
    for (int k = 0; k < 8; ++k) { dm[k] = (f32x2)(1e30f); vs[k] = (f32x2)(0.f); }

    int p = 0;
    for (int gx = 0; gx < 10; ++gx) {
        const int sxg = gx - 5;
        f32x2 sC[23];                        // shifted column, one load / 10 slots
        if (is1) {
            const int cs = c1 + 4 - sxg;     // 0..46, in range
#pragma unroll
            for (int t = 0; t < 23; ++t) sC[t] = L2[(r0 + t) * LSTR2 + cs];
        }
#pragma unroll
        for (int j = 0; j < 10; ++j) {
            const int sy = j - 5;
            if (sxg == 0 && sy == 0) continue;       // uniform skip (incl. barrier)
            const int off = 9 - j;                   // compile-time
            if (is1) {
                f32x2 d[14];
#pragma unroll
                for (int a = 0; a < 14; ++a) {
                    f32x2 dd = cC[a] - sC[a + off];
                    d[a] = dd * dd;
                }
                f32x2* w = &TB[p][r0 * TSTR2 + c1];
#pragma unroll
                for (int k = 0; k < 8; ++k) w[k * TSTR2] = tap7p(d + k);
            }
            __syncthreads();                 // slot p ready; WAR safe (see header)
            if (is2) {
                f32x2 D[8]; S2(p, D);
                const bool card = (sxg * sxg + sy * sy) == 1;
#pragma unroll
                for (int k = 0; k < 8; ++k) {
                    dm[k] = __builtin_elementwise_min(dm[k], D[k]);
                    if (card) vs[k] += D[k];
                }
            }
            p ^= 1;
        }
    }

    // loss constants; invalid pixels rv=0 -> ep=eg=exp2(0)=1 -> |ep-eg|=0
    float rvp[8], rvg[8];
#pragma unroll
    for (int k = 0; k < 8; ++k) {
        const int oy = oy0 + dv_r, ox = ox0 + oc * 8 + k;
        const bool valid = is2 && (oy < OUTD) && (ox < OUTD);
        rvp[k] = valid ? LOG2E / (vs[k].x * 0.25f + 1e-5f) : 0.f;
        rvg[k] = valid ? LOG2E / (vs[k].y * 0.25f + 1e-5f) : 0.f;
    }

    __syncthreads();   // phase boundary: slot-98 reads (TB[0]) vs B's first write

    // ---- phase B: recompute D, accumulate |exp2((m-D)*rv)p - (...)g| ----
    float acc = 0.f;
    p = 0;
    for (int gx = 0; gx < 10; ++gx) {
        const int sxg = gx - 5;
        f32x2 sC[23];
        if (is1) {
            const int cs = c1 + 4 - sxg;
#pragma unroll
            for (int t = 0; t < 23; ++t) sC[t] = L2[(r0 + t) * LSTR2 + cs];
        }
#pragma unroll
        for (int j = 0; j < 10; ++j) {
            const int sy = j - 5;
            if (sxg == 0 && sy == 0) continue;
            const int off = 9 - j;
            if (is1) {
                f32x2 d[14];
#pragma unroll
                for (int a = 0; a < 14; ++a) {
                    f32x2 dd = cC[a] - sC[a + off];
                    d[a] = dd * dd;
                }
                f32x2* w = &TB[p][r0 * TSTR2 + c1];
#pragma unroll
                for (int k = 0; k < 8; ++k) w[k * TSTR2] = tap7p(d + k);
            }
            __syncthreads();
            if (is2) {
                f32x2 D[8]; S2(p, D);
#pragma unroll
                for (int k = 0; k < 8; ++k) {
                    float ep = exp2f((dm[k].x - D[k].x) * rvp[k]);
                    float eg = exp2f((dm[k].y - D[k].y) * rvg[k]);
                    acc += fabsf(ep - eg);
                }
            }
            p ^= 1;
        }
    }

#pragma unroll
    for (int off = 32; off > 0; off >>= 1) acc += __shfl_down(acc, off, 64);
    const int lane = tid & 63, wv = tid >> 6;
    if (lane == 0) wred[wv] = acc;
    __syncthreads();
    if (tid == 0) {
        const float SC = (float)(1.0 / 54212400.0);  // 1/(4*370*370*99)
        atomicAdd(out, (wred[0] + wred[1] + wred[2] + wred[3]) * SC);
    }
}

extern "C" void kernel_launch(void* const* d_in, const int* in_sizes, int n_in,
                              void* d_out, int out_size, void* d_ws, size_t ws_size,
                              hipStream_t stream)
{
    (void)in_sizes; (void)n_in; (void)out_size; (void)d_ws; (void)ws_size;
    const float* pred = (const float*)d_in[0];
    const float* gt   = (const float*)d_in[1];
    float* out = (float*)d_out;

    hipMemsetAsync(d_out, 0, sizeof(float), stream);

    dim3 g(NXT * NYT, 4, 1);   // 192 tiles x 4 batch = 768 blocks = 3/CU exact
    mind_fused<<<g, 256, 0, stream>>>(pred, gt, out);
}